// Round 8
// baseline (105.967 us; speedup 1.0000x reference)
//
#include <hip/hip_runtime.h>
#include <math.h>

#define HID 512
#define IN_FEAT 342
#define OUTD 311
#define BATCH 256
#define XROW (IN_FEAT + 1)
#define KP0 352            // layer-0 padded K (11 chunks of 32)

typedef unsigned short u16;
typedef short bf16x8 __attribute__((ext_vector_type(8)));
typedef float f32x4 __attribute__((ext_vector_type(4)));

__device__ __forceinline__ u16 f2bf_rne(float v) {
    unsigned int x = __float_as_uint(v);
    unsigned int r = (x + 0x7fffu + ((x >> 16) & 1u)) >> 16;
    return (u16)r;
}
__device__ __forceinline__ float bf2f(u16 u) {
    return __uint_as_float(((unsigned int)u) << 16);
}

// in-register fp32 -> (hi RNE, lo trunc) split of 8 elems
__device__ __forceinline__ void cvt8(const float* v, bf16x8& hi, bf16x8& lo) {
#pragma unroll
    for (int j = 0; j < 8; j++) {
        unsigned int xu = __float_as_uint(v[j]);
        unsigned int rnd = xu + 0x7fffu + ((xu >> 16) & 1u);
        hi[j] = (short)(rnd >> 16);
        float lof = v[j] - __uint_as_float(rnd & 0xffff0000u);
        lo[j] = (short)(__float_as_uint(lof) >> 16);   // trunc: |err| <= 2^-17 rel
    }
}

// grid-stride conversion tail: contiguous fp32 array -> hi/lo bf16 (8-wide chunks)
__device__ __forceinline__ void conv_tail(const float* __restrict__ src,
                                          u16* __restrict__ dhi, u16* __restrict__ dlo,
                                          int nchunks)
{
    const int bid = (int)blockIdx.y * (int)gridDim.x + (int)blockIdx.x;
    const int nthr = (int)gridDim.x * (int)gridDim.y * 256;
    for (int i = bid * 256 + (int)threadIdx.x; i < nchunks; i += nthr) {
        const float* p = src + (size_t)i * 8;
        float4 f0 = *reinterpret_cast<const float4*>(p);
        float4 f1 = *reinterpret_cast<const float4*>(p + 4);
        float v[8] = {f0.x, f0.y, f0.z, f0.w, f1.x, f1.y, f1.z, f1.w};
        bf16x8 hi, lo;
        cvt8(v, hi, lo);
        *reinterpret_cast<bf16x8*>(dhi + (size_t)i * 8) = hi;
        *reinterpret_cast<bf16x8*>(dlo + (size_t)i * 8) = lo;
    }
}

// ============ fused layer ============
// out[b][o] = act( sum_s d_s(b) * ( sum_k W[s][o][k]*H[b][k] + bias[s][o] ) )
// grid (BATCH/16, ceil(M/16)); block 256 = 4 waves; wave s = slice s; LDS blend.
// MODE 0: W fp32 in-loop convert (L0), H from x. MODE 1: bf16 W/H, emit bf16 H.
// MODE 2: bf16 W/H, emit fp32 out.  Optional conversion tail for next layer's W.
template<int KCH, int KLDS, int MODE>
__global__ __launch_bounds__(256, 2) void layer_k(
    const float* __restrict__ Wf,
    const u16* __restrict__ Whi, const u16* __restrict__ Wlo,
    int Wrows,                         // rows per slice in W layout
    const float* __restrict__ x,       // [256][343] (H-source L0; phase col always)
    const u16* __restrict__ Hhi, const u16* __restrict__ Hlo,
    const float* __restrict__ bias, int Mb,
    u16* __restrict__ Ohi, u16* __restrict__ Olo, float* __restrict__ outp,
    const float* __restrict__ Tsrc, u16* __restrict__ Thi, u16* __restrict__ Tlo,
    int Tchunks)
{
    union SharedU {
        u16 h[2][16 * KLDS];
        float acc[4][16][17];
    };
    __shared__ SharedU sm;

    const int tid = (int)threadIdx.x;
    const int b0 = (int)blockIdx.x * 16;
    const int o0 = (int)blockIdx.y * 16;

    // ---- stage H tile (16 rows x KCH*32, hi+lo) ----
    if (MODE == 0) {
        for (int idx = tid; idx < 16 * KP0; idx += 256) {
            int r = idx / KP0, k = idx - r * KP0;
            float v = (k < IN_FEAT) ? x[(size_t)(b0 + r) * XROW + k] : 0.f;
            u16 h = f2bf_rne(v);
            sm.h[0][r * KLDS + k] = h;
            sm.h[1][r * KLDS + k] = f2bf_rne(v - bf2f(h));
        }
    } else {
        constexpr int CH = KCH * 4;          // uint4 per row
        for (int idx = tid; idx < 16 * CH; idx += 256) {
            int r = idx / CH, c = idx - r * CH;
            size_t g = (size_t)(b0 + r) * HID + c * 8;
            *reinterpret_cast<uint4*>(&sm.h[0][r * KLDS + c * 8]) =
                *reinterpret_cast<const uint4*>(Hhi + g);
            *reinterpret_cast<uint4*>(&sm.h[1][r * KLDS + c * 8]) =
                *reinterpret_cast<const uint4*>(Hlo + g);
        }
    }
    __syncthreads();

    const int lane = tid & 63;
    const int s = tid >> 6;               // wave -> slice
    const int m = lane & 15;
    const int q = lane >> 4;

    int orow = o0 + m;
    if (orow >= Wrows) orow = Wrows - 1;  // clamp: duplicate row, results discarded

    const u16* hp = &sm.h[0][m * KLDS + q * 8];

    f32x4 a0 = {0.f, 0.f, 0.f, 0.f};
    f32x4 a1 = {0.f, 0.f, 0.f, 0.f};
    f32x4 a2 = {0.f, 0.f, 0.f, 0.f};

    if (MODE == 0) {
        const float* wr = Wf + ((size_t)s * Wrows + orow) * IN_FEAT;
#pragma unroll
        for (int cc = 0; cc < KCH; ++cc) {
            const int kb = cc * 32 + q * 8;
            float v[8];
            if (cc < KCH - 1) {           // full chunk: float2 x4 (rows 8B-aligned)
#pragma unroll
                for (int t = 0; t < 4; t++) {
                    float2 f2 = *reinterpret_cast<const float2*>(wr + kb + t * 2);
                    v[t * 2] = f2.x; v[t * 2 + 1] = f2.y;
                }
            } else {                      // tail chunk (K=342): per-elem guard
#pragma unroll
                for (int j = 0; j < 8; j++) {
                    int k = kb + j;
                    v[j] = (k < IN_FEAT) ? wr[k] : 0.f;
                }
            }
            bf16x8 ah, al;
            cvt8(v, ah, al);
            bf16x8 bh = *reinterpret_cast<const bf16x8*>(hp + cc * 32);
            bf16x8 bl = *reinterpret_cast<const bf16x8*>(hp + cc * 32 + 16 * KLDS);
            a0 = __builtin_amdgcn_mfma_f32_16x16x32_bf16(ah, bh, a0, 0, 0, 0);
            a1 = __builtin_amdgcn_mfma_f32_16x16x32_bf16(ah, bl, a1, 0, 0, 0);
            a2 = __builtin_amdgcn_mfma_f32_16x16x32_bf16(al, bh, a2, 0, 0, 0);
        }
    } else {
        const size_t wro = ((size_t)s * Wrows + orow) * (KCH * 32) + q * 8;
        const u16* wph = Whi + wro;
        const u16* wpl = Wlo + wro;
#pragma unroll
        for (int cc = 0; cc < KCH; ++cc) {
            bf16x8 ah = *reinterpret_cast<const bf16x8*>(wph + cc * 32);
            bf16x8 al = *reinterpret_cast<const bf16x8*>(wpl + cc * 32);
            bf16x8 bh = *reinterpret_cast<const bf16x8*>(hp + cc * 32);
            bf16x8 bl = *reinterpret_cast<const bf16x8*>(hp + cc * 32 + 16 * KLDS);
            a0 = __builtin_amdgcn_mfma_f32_16x16x32_bf16(ah, bh, a0, 0, 0, 0);
            a1 = __builtin_amdgcn_mfma_f32_16x16x32_bf16(ah, bl, a1, 0, 0, 0);
            a2 = __builtin_amdgcn_mfma_f32_16x16x32_bf16(al, bh, a2, 0, 0, 0);
        }
    }
    __syncthreads();   // LDS H reads done; reuse union as blend buffer

    // per-lane phase coeff d_s(b), b = b0+m  (s is wave-uniform)
    float ds;
    {
        float ps = 4.f * x[(size_t)(b0 + m) * XROW + IN_FEAT];
        float fl = floorf(ps);
        float mu = ps - fl;
        int i1 = ((int)fl) & 3;
        float mu2 = mu * mu, mu3 = mu2 * mu;
        float c0 = -0.5f * mu3 + mu2 - 0.5f * mu;
        float c1 = 1.5f * mu3 - 2.5f * mu2 + 1.0f;
        float c2 = -1.5f * mu3 + 2.0f * mu2 + 0.5f * mu;
        float c3 = 0.5f * mu3 - 0.5f * mu2;
        int k = (s + 1 - i1) & 3;         // slice s gets c[k]
        ds = (k == 0) ? c0 : (k == 1) ? c1 : (k == 2) ? c2 : c3;
    }

    f32x4 sum = a0 + a1 + a2;
#pragma unroll
    for (int r = 0; r < 4; ++r) {
        int o = o0 + q * 4 + r;
        float bb = (o < Mb) ? bias[(size_t)s * Mb + o] : 0.f;
        sm.acc[s][q * 4 + r][m] = ds * (sum[r] + bb);
    }
    __syncthreads();

    // reduce 4 slices, activate, store: thread -> (b_l = tid>>4, o_l = tid&15)
    const int o_l = tid & 15;
    const int b_l = tid >> 4;
    float vv = sm.acc[0][o_l][b_l] + sm.acc[1][o_l][b_l]
             + sm.acc[2][o_l][b_l] + sm.acc[3][o_l][b_l];
    const int o = o0 + o_l;
    const int b = b0 + b_l;
    if (MODE != 2) {
        float e = (vv > 0.f) ? vv : expm1f(vv);
        u16 h = f2bf_rne(e);
        Ohi[(size_t)b * HID + o] = h;
        Olo[(size_t)b * HID + o] = f2bf_rne(e - bf2f(h));
    } else if (o < OUTD) {
        outp[(size_t)b * OUTD + o] = vv;
    }

    // ---- conversion tail for next layer's W (independent work, no barrier) ----
    if (MODE != 2 && Tchunks > 0)
        conv_tail(Tsrc, Thi, Tlo, Tchunks);
}

extern "C" void kernel_launch(void* const* d_in, const int* in_sizes, int n_in,
                              void* d_out, int out_size, void* d_ws, size_t ws_size,
                              hipStream_t stream) {
    const float* x  = (const float*)d_in[0];
    const float* W0 = (const float*)d_in[1];
    const float* b0 = (const float*)d_in[2];
    const float* W1 = (const float*)d_in[3];
    const float* b1 = (const float*)d_in[4];
    const float* W2 = (const float*)d_in[5];
    const float* b2 = (const float*)d_in[6];
    float* out = (float*)d_out;

    char* pw = (char*)d_ws;
    auto alloc = [&](size_t bytes) { char* r = pw; pw += (bytes + 255) & ~(size_t)255; return r; };
    u16* whi1 = (u16*)alloc((size_t)4 * HID * HID * 2);
    u16* wlo1 = (u16*)alloc((size_t)4 * HID * HID * 2);
    u16* whi2 = (u16*)alloc((size_t)4 * OUTD * HID * 2);
    u16* wlo2 = (u16*)alloc((size_t)4 * OUTD * HID * 2);
    u16* hahi = (u16*)alloc((size_t)BATCH * HID * 2);
    u16* halo = (u16*)alloc((size_t)BATCH * HID * 2);
    u16* hbhi = (u16*)alloc((size_t)BATCH * HID * 2);
    u16* hblo = (u16*)alloc((size_t)BATCH * HID * 2);

    const int W1_CHUNKS = 4 * HID * HID / 8;    // 131072 = 512 blk * 256 thr
    const int W2_CHUNKS = 4 * OUTD * HID / 8;   // 79616

    // L0: W0 fp32 in-loop, converts W1 in tail. grid (16,32)=512 blocks
    layer_k<11, 360, 0><<<dim3(BATCH / 16, HID / 16), 256, 0, stream>>>(
        W0, nullptr, nullptr, HID, x, nullptr, nullptr, b0, HID,
        hahi, halo, nullptr, W1, whi1, wlo1, W1_CHUNKS);

    // L1: clean bf16, converts W2 in tail. grid (16,32)
    layer_k<16, 520, 1><<<dim3(BATCH / 16, HID / 16), 256, 0, stream>>>(
        nullptr, whi1, wlo1, HID, x, hahi, halo, b1, HID,
        hbhi, hblo, nullptr, W2, whi2, wlo2, W2_CHUNKS);

    // L2: clean bf16, M=311 (20 o-tiles), fp32 out. grid (16,20)
    layer_k<16, 520, 2><<<dim3(BATCH / 16, 20), 256, 0, stream>>>(
        nullptr, whi2, wlo2, OUTD, x, hbhi, hblo, b2, OUTD,
        nullptr, nullptr, out, nullptr, nullptr, nullptr, 0);
}

// Round 9
// 102.142 us; speedup vs baseline: 1.0374x; 1.0374x over previous
//
#include <hip/hip_runtime.h>
#include <math.h>

#define HID 512
#define IN_FEAT 342
#define OUTD 311
#define BATCH 256
#define KP0 352           // layer-0 padded K (11 chunks of 32)
#define MP2 320           // layer-2 padded M
#define XROW (IN_FEAT + 1)

typedef unsigned short u16;
typedef short bf16x8 __attribute__((ext_vector_type(8)));
typedef float f32x4 __attribute__((ext_vector_type(4)));

__device__ __forceinline__ u16 f2bf_rne(float v) {
    unsigned int x = __float_as_uint(v);
    unsigned int r = (x + 0x7fffu + ((x >> 16) & 1u)) >> 16;
    return (u16)r;
}
__device__ __forceinline__ float bf2f(u16 u) {
    return __uint_as_float(((unsigned int)u) << 16);
}

// ================= combined prep (R5 verbatim) =================
#define C0 (4 * 512 * 44)
#define C1 (4 * 512 * 64)
#define C2 (4 * 320 * 64)
#define CX (256 * 44)
#define PREP_TOT (C0 + C1 + C2 + CX + 256)

union U8 { u16 u[8]; uint4 v; };

__global__ __launch_bounds__(256) void prep_all(
    const float* __restrict__ x,
    const float* __restrict__ W0, const float* __restrict__ W1, const float* __restrict__ W2,
    u16* __restrict__ whi0, u16* __restrict__ wlo0,
    u16* __restrict__ whi1, u16* __restrict__ wlo1,
    u16* __restrict__ whi2, u16* __restrict__ wlo2,
    u16* __restrict__ h0hi, u16* __restrict__ h0lo,
    float* __restrict__ dcoef)
{
    int i = blockIdx.x * 256 + threadIdx.x;
    if (i >= PREP_TOT) return;

    if (i >= C0 + C1 + C2 + CX) {           // ---- dcoef ----
        int b = i - (C0 + C1 + C2 + CX);
        float ps = 4.f * x[(size_t)b * XROW + IN_FEAT];
        float fl = floorf(ps);
        float mu = ps - fl;
        int i1 = ((int)fl) & 3;
        float mu2 = mu * mu, mu3 = mu2 * mu;
        float c0 = -0.5f * mu3 + mu2 - 0.5f * mu;
        float c1 = 1.5f * mu3 - 2.5f * mu2 + 1.0f;
        float c2 = -1.5f * mu3 + 2.0f * mu2 + 0.5f * mu;
        float c3 = 0.5f * mu3 - 0.5f * mu2;
        float d[4];
        d[(i1 + 3) & 3] = c0;
        d[i1]           = c1;
        d[(i1 + 1) & 3] = c2;
        d[(i1 + 2) & 3] = c3;
        *reinterpret_cast<float4*>(dcoef + b * 4) = make_float4(d[0], d[1], d[2], d[3]);
        return;
    }

    float src[8];
    u16 *dhi, *dlo; size_t doff;
    if (i < C0) {                            // ---- W0 -> [4*512][352] ----
        int row = i / 44, c = i - row * 44;
        int k = c * 8;
#pragma unroll
        for (int j = 0; j < 8; j++) {
            int kk = k + j;
            src[j] = (kk < IN_FEAT) ? W0[(size_t)row * IN_FEAT + kk] : 0.f;
        }
        dhi = whi0; dlo = wlo0; doff = (size_t)row * KP0 + k;
    } else if (i < C0 + C1) {                // ---- W1 -> [4*512][512] ----
        int l = i - C0;
        int row = l >> 6, c = l & 63;
        int k = c * 8;
        const float* p = W1 + (size_t)row * HID + k;
#pragma unroll
        for (int j = 0; j < 8; j++) src[j] = p[j];
        dhi = whi1; dlo = wlo1; doff = (size_t)row * HID + k;
    } else if (i < C0 + C1 + C2) {           // ---- W2 -> [4*320][512] (rows>=311 zero) ----
        int l = i - C0 - C1;
        int row = l >> 6, c = l & 63;
        int k = c * 8;
        int s = row / 320, o = row - s * 320;
        if (o < OUTD) {
            const float* p = W2 + ((size_t)s * OUTD + o) * HID + k;
#pragma unroll
            for (int j = 0; j < 8; j++) src[j] = p[j];
        } else {
#pragma unroll
            for (int j = 0; j < 8; j++) src[j] = 0.f;
        }
        dhi = whi2; dlo = wlo2; doff = (size_t)row * HID + k;
    } else {                                 // ---- x -> H0 [256][352] ----
        int l = i - C0 - C1 - C2;
        int b = l / 44, c = l - b * 44;
        int k = c * 8;
#pragma unroll
        for (int j = 0; j < 8; j++) {
            int kk = k + j;
            src[j] = (kk < IN_FEAT) ? x[(size_t)b * XROW + kk] : 0.f;
        }
        dhi = h0hi; dlo = h0lo; doff = (size_t)b * KP0 + k;
    }

    U8 hi, lo;
#pragma unroll
    for (int j = 0; j < 8; j++) {
        u16 h = f2bf_rne(src[j]);
        hi.u[j] = h;
        lo.u[j] = f2bf_rne(src[j] - bf2f(h));
    }
    *reinterpret_cast<uint4*>(dhi + doff) = hi.v;
    *reinterpret_cast<uint4*>(dlo + doff) = lo.v;
}

// ========== fused layer v3: NB batch rows/block, NB*16 threads, wave=(slice, b-half) ==========
// out[b][o] = act( sum_s d_s(b) * ( sum_k W[s][o][k]*H[b][k] + bias[s][o] ) )
// grid (BATCH/NB, Mp/16). NB=32: 8 waves, pairs (w, w+4) share slice s=w&3 -> W L1 reuse.
// NB=16: 4 waves (R5 shape). H tile (NB rows x KP hi+lo) in LDS, row stride KLDS
// (odd 16B quads -> conflict-free). Cross-slice blend via LDS union.
template<int KP, int KLDS, int NB, int FINAL>
__global__ __launch_bounds__(NB * 16, (NB == 16 ? 2 : 1)) void layer_v3(
    const u16* __restrict__ Whi, const u16* __restrict__ Wlo, int Mp,
    const u16* __restrict__ Hhi, const u16* __restrict__ Hlo,
    const float* __restrict__ bias, const float* __restrict__ dcoef, int Mb,
    u16* __restrict__ Ohi, u16* __restrict__ Olo, float* __restrict__ outp)
{
    union SharedU {
        u16 h[2][NB * KLDS];
        float acc[4][NB][17];
    };
    __shared__ SharedU sm;

    const int tid = (int)threadIdx.x;
    const int b0 = (int)blockIdx.x * NB;
    const int o0 = (int)blockIdx.y * 16;
    constexpr int NTHR = NB * 16;

    // ---- stage H tile (NB rows x KP, hi+lo) ----
    constexpr int CH = KP / 8;                // uint4 per row
    for (int idx = tid; idx < NB * CH; idx += NTHR) {
        int r = idx / CH, c = idx - r * CH;
        size_t g = (size_t)(b0 + r) * KP + c * 8;
        *reinterpret_cast<uint4*>(&sm.h[0][r * KLDS + c * 8]) =
            *reinterpret_cast<const uint4*>(Hhi + g);
        *reinterpret_cast<uint4*>(&sm.h[1][r * KLDS + c * 8]) =
            *reinterpret_cast<const uint4*>(Hlo + g);
    }
    __syncthreads();

    const int lane = tid & 63;
    const int w = tid >> 6;
    const int s = w & 3;                      // slice
    const int t = w >> 2;                     // b-half (0 for NB=16)
    const int m = lane & 15;
    const int q = lane >> 4;

    const size_t wro = ((size_t)s * Mp + o0 + m) * KP + q * 8;
    const u16* wph = Whi + wro;
    const u16* wpl = Wlo + wro;
    const u16* hp = &sm.h[0][(t * 16 + m) * KLDS + q * 8];

    f32x4 a0 = {0.f, 0.f, 0.f, 0.f};
    f32x4 a1 = {0.f, 0.f, 0.f, 0.f};
    f32x4 a2 = {0.f, 0.f, 0.f, 0.f};
#pragma unroll
    for (int cc = 0; cc < KP / 32; ++cc) {
        bf16x8 ah = *reinterpret_cast<const bf16x8*>(wph + cc * 32);
        bf16x8 al = *reinterpret_cast<const bf16x8*>(wpl + cc * 32);
        bf16x8 bh = *reinterpret_cast<const bf16x8*>(hp + cc * 32);
        bf16x8 bl = *reinterpret_cast<const bf16x8*>(hp + cc * 32 + NB * KLDS);
        a0 = __builtin_amdgcn_mfma_f32_16x16x32_bf16(ah, bh, a0, 0, 0, 0);
        a1 = __builtin_amdgcn_mfma_f32_16x16x32_bf16(ah, bl, a1, 0, 0, 0);
        a2 = __builtin_amdgcn_mfma_f32_16x16x32_bf16(al, bh, a2, 0, 0, 0);
    }
    __syncthreads();   // LDS H reads done; reuse union as blend buffer

    // wave-phase blend: d_s(b) * (sum + bias_s). C layout: col=lane&15 (b), row=q*4+r (o).
    const float ds = dcoef[(size_t)(b0 + t * 16 + m) * 4 + s];
    f32x4 sum = a0 + a1 + a2;
#pragma unroll
    for (int r = 0; r < 4; ++r) {
        int o = o0 + q * 4 + r;
        float bb = (o < Mb) ? bias[(size_t)s * Mb + o] : 0.f;
        sm.acc[s][t * 16 + m][q * 4 + r] = ds * (sum[r] + bb);
    }
    __syncthreads();

    // reduce 4 slices, activate, store: thread -> (b_l = tid>>4, o_l = tid&15)
    const int b_l = tid >> 4;
    const int o_l = tid & 15;
    float vv = sm.acc[0][b_l][o_l] + sm.acc[1][b_l][o_l]
             + sm.acc[2][b_l][o_l] + sm.acc[3][b_l][o_l];
    const int o = o0 + o_l;
    const int b = b0 + b_l;
    if (!FINAL) {
        float e = (vv > 0.f) ? vv : expm1f(vv);
        u16 h = f2bf_rne(e);
        Ohi[(size_t)b * HID + o] = h;
        Olo[(size_t)b * HID + o] = f2bf_rne(e - bf2f(h));
    } else if (o < OUTD) {
        outp[(size_t)b * OUTD + o] = vv;
    }
}

extern "C" void kernel_launch(void* const* d_in, const int* in_sizes, int n_in,
                              void* d_out, int out_size, void* d_ws, size_t ws_size,
                              hipStream_t stream) {
    const float* x  = (const float*)d_in[0];
    const float* W0 = (const float*)d_in[1];
    const float* b0 = (const float*)d_in[2];
    const float* W1 = (const float*)d_in[3];
    const float* b1 = (const float*)d_in[4];
    const float* W2 = (const float*)d_in[5];
    const float* b2 = (const float*)d_in[6];
    float* out = (float*)d_out;

    char* pw = (char*)d_ws;
    auto alloc = [&](size_t bytes) { char* r = pw; pw += (bytes + 255) & ~(size_t)255; return r; };

    float* dcoef = (float*)alloc(BATCH * 4 * sizeof(float));
    u16* whi0 = (u16*)alloc((size_t)4 * HID * KP0 * 2);
    u16* wlo0 = (u16*)alloc((size_t)4 * HID * KP0 * 2);
    u16* whi1 = (u16*)alloc((size_t)4 * HID * HID * 2);
    u16* wlo1 = (u16*)alloc((size_t)4 * HID * HID * 2);
    u16* whi2 = (u16*)alloc((size_t)4 * MP2 * HID * 2);
    u16* wlo2 = (u16*)alloc((size_t)4 * MP2 * HID * 2);
    u16* h0hi = (u16*)alloc((size_t)BATCH * KP0 * 2);
    u16* h0lo = (u16*)alloc((size_t)BATCH * KP0 * 2);
    u16* hahi = (u16*)alloc((size_t)BATCH * HID * 2);
    u16* halo = (u16*)alloc((size_t)BATCH * HID * 2);
    u16* hbhi = (u16*)alloc((size_t)BATCH * HID * 2);
    u16* hblo = (u16*)alloc((size_t)BATCH * HID * 2);

    prep_all<<<dim3((PREP_TOT + 255) / 256), 256, 0, stream>>>(
        x, W0, W1, W2, whi0, wlo0, whi1, wlo1, whi2, wlo2, h0hi, h0lo, dcoef);

    // L0: K=352, M=512, NB=32 -> grid (8,32)=256 blocks, 512 thr
    layer_v3<KP0, 360, 32, 0><<<dim3(BATCH / 32, HID / 16), 512, 0, stream>>>(
        whi0, wlo0, HID, h0hi, h0lo, b0, dcoef, HID, hahi, halo, nullptr);

    // L1: K=512, M=512, NB=32 -> grid (8,32)=256 blocks, 512 thr
    layer_v3<HID, 520, 32, 0><<<dim3(BATCH / 32, HID / 16), 512, 0, stream>>>(
        whi1, wlo1, HID, hahi, halo, b1, dcoef, HID, hbhi, hblo, nullptr);

    // L2: K=512, M=311 (Mp=320), NB=16 -> grid (16,20)=320 blocks, 256 thr (R5 shape)
    layer_v3<HID, 520, 16, 1><<<dim3(BATCH / 16, MP2 / 16), 256, 0, stream>>>(
        whi2, wlo2, MP2, hbhi, hblo, b2, dcoef, OUTD, nullptr, nullptr, out);
}